// Round 1
// baseline (435.286 us; speedup 1.0000x reference)
//
#include <hip/hip_runtime.h>

// fp8 blockwise-quantized GEMM for MI355X (gfx950)
//   y = (fp8(x/sx)*sx) @ (fp8(w)*sw)^T,  sx per (row,128-block of K), sw per 128x128 block
// Strategy: quantize x and w to e4m3fn in workspace, then MX-MFMA GEMM
// (mfma_scale_f32_16x16x128_f8f6f4 with unit e8m0 scales = plain fp8 K=128 dot
//  at the 2x MX rate), applying the exact f32 combined scale per K=128 block.

#define GLOBAL_AS __attribute__((address_space(1)))
#define LDS_AS    __attribute__((address_space(3)))

typedef int   v4i __attribute__((ext_vector_type(4)));
typedef int   v8i __attribute__((ext_vector_type(8)));
typedef float v4f __attribute__((ext_vector_type(4)));

constexpr int M  = 8192;
constexpr int K  = 4096;
constexpr int N  = 4096;
constexpr int KB = K / 128;  // 32
constexpr int NB = N / 128;  // 32

__device__ __forceinline__ void async16(const void* g, void* l) {
  // 16B/lane global->LDS DMA; LDS dest = wave-uniform base + lane*16
  __builtin_amdgcn_global_load_lds((const GLOBAL_AS void*)g, (LDS_AS void*)l, 16, 0, 0);
}

// ---------------- activation blockwise quant ----------------
// one half-wave (32 lanes) per 128-elem block; lane holds 4 consecutive f32
__global__ __launch_bounds__(256) void quant_x_kernel(
    const float* __restrict__ x, unsigned char* __restrict__ xq,
    float* __restrict__ xs_t /* [KB][M] */) {
  const int tid = threadIdx.x;
  const long long blk = (long long)blockIdx.x * 8 + (tid >> 5);  // over M*KB blocks
  const int l = tid & 31;
  const float4 v = ((const float4*)(x + blk * 128))[l];
  float ax = fmaxf(fmaxf(fabsf(v.x), fabsf(v.y)), fmaxf(fabsf(v.z), fabsf(v.w)));
#pragma unroll
  for (int s = 16; s >= 1; s >>= 1) ax = fmaxf(ax, __shfl_xor(ax, s, 32));
  // match reference bit-for-bit: scale = max(amax,1e-12)/448 (true divisions, RNE)
  const float scale = fmaxf(ax, 1e-12f) / 448.0f;
  int p = 0;
  p = __builtin_amdgcn_cvt_pk_fp8_f32(v.x / scale, v.y / scale, p, false);
  p = __builtin_amdgcn_cvt_pk_fp8_f32(v.z / scale, v.w / scale, p, true);
  ((int*)(xq + blk * 128))[l] = p;
  if (l == 0) {
    const int m  = (int)(blk >> 5);        // KB = 32
    const int kb = (int)(blk & (KB - 1));
    xs_t[(long long)kb * M + m] = scale;   // transposed for coalesced GEMM reads
  }
}

// ---------------- weight fp8 cast ----------------
__global__ __launch_bounds__(256) void quant_w_kernel(
    const float* __restrict__ w, unsigned char* __restrict__ wq) {
  const long long i = (long long)blockIdx.x * 256 + threadIdx.x;  // float4 groups
  const float4 v = ((const float4*)w)[i];
  int p = 0;
  p = __builtin_amdgcn_cvt_pk_fp8_f32(v.x, v.y, p, false);
  p = __builtin_amdgcn_cvt_pk_fp8_f32(v.z, v.w, p, true);
  ((int*)wq)[i] = p;
}

// ---------------- fp8 GEMM with per-128-block f32 rescale ----------------
// grid (N/128, M/128), 256 threads = 4 waves in 2x2; wave computes 64x64.
// LDS tiles hold fp8 rows in 16B chunks with XOR swizzle: chunk' = chunk ^ (row&7)
// (realized by permuting lanes' global addresses in global_load_lds), so the
// fragment ds_read_b128s spread across all 32 banks (2-way = free).
__global__ __launch_bounds__(256, 2) void gemm_fp8_kernel(
    const unsigned char* __restrict__ xq, const unsigned char* __restrict__ wq,
    const float* __restrict__ xs_t /*[KB][M]*/,
    const float* __restrict__ wscale /*[NB][KB]*/,
    float* __restrict__ out) {
  __shared__ unsigned char Asm[128 * 128];  // 16 KB
  __shared__ unsigned char Bsm[128 * 128];  // 16 KB
  __shared__ float Ssm[KB * 128];           // 16 KB combined scales [kb][row]

  const int tid   = threadIdx.x;
  const int ntile = blockIdx.x;  // 0..31 (also the nb scale-block index)
  const int mtile = blockIdx.y;  // 0..63
  const int wave  = tid >> 6;
  const int lane  = tid & 63;
  const int wm = wave >> 1, wn = wave & 1;
  const int l15 = lane & 15, quad = lane >> 4;

  // ---- one-time: combined scales Ssm[kb*128+r] = xs[m,kb] * wsc[nb,kb] ----
  for (int i = tid; i < KB * 128; i += 256) {
    const int kb = i >> 7, r = i & 127;
    Ssm[i] = xs_t[(long long)kb * M + mtile * 128 + r] * wscale[ntile * KB + kb];
  }

  // ---- staging addresses: wave stages rows [wave*32, wave*32+32) of each tile
  // lane i covers (row8 = i>>3, chunk' = i&7); global chunk = chunk' ^ (row8)
  const int s_r8 = lane >> 3, s_ch = lane & 7;
  const unsigned char* pa[4];
  const unsigned char* pb[4];
#pragma unroll
  for (int t = 0; t < 4; ++t) {
    const int lrow = wave * 32 + t * 8 + s_r8;           // local row 0..127
    const int cc   = ((s_ch ^ s_r8) << 4);               // swizzled k-chunk byte
    pa[t] = xq + (long long)(mtile * 128 + lrow) * K + cc;
    pb[t] = wq + (long long)(ntile * 128 + lrow) * K + cc;
  }
  const int lds_base = wave * 32 * 128;  // + t*1024

  // ---- fragment LDS offsets (kb-invariant) ----
  int aoff[4][2], boff[4][2], soff[4];
#pragma unroll
  for (int f = 0; f < 4; ++f) {
    const int m_loc = wm * 64 + f * 16 + l15;
    const int n_loc = wn * 64 + f * 16 + l15;
    aoff[f][0] = m_loc * 128 + (((quad * 2 + 0) ^ (m_loc & 7)) << 4);
    aoff[f][1] = m_loc * 128 + (((quad * 2 + 1) ^ (m_loc & 7)) << 4);
    boff[f][0] = n_loc * 128 + (((quad * 2 + 0) ^ (n_loc & 7)) << 4);
    boff[f][1] = n_loc * 128 + (((quad * 2 + 1) ^ (n_loc & 7)) << 4);
    soff[f] = wm * 64 + f * 16 + quad * 4;  // C/D row = quad*4 + reg
  }

  v4f acc[4][4];
#pragma unroll
  for (int f = 0; f < 4; ++f)
#pragma unroll
    for (int g = 0; g < 4; ++g) acc[f][g] = (v4f){0.f, 0.f, 0.f, 0.f};

  for (int kb = 0; kb < KB; ++kb) {
    const int koff = kb * 128;
    // stage A+B tiles (8 x 1KB per wave)
#pragma unroll
    for (int t = 0; t < 4; ++t) {
      async16(pa[t] + koff, Asm + lds_base + t * 1024);
      async16(pb[t] + koff, Bsm + lds_base + t * 1024);
    }
    __syncthreads();  // drains vmcnt: staging complete

    v8i a[4], b[4];
#pragma unroll
    for (int f = 0; f < 4; ++f) {
      v4i lo = *(const v4i*)(Asm + aoff[f][0]);
      v4i hi = *(const v4i*)(Asm + aoff[f][1]);
      a[f][0] = lo[0]; a[f][1] = lo[1]; a[f][2] = lo[2]; a[f][3] = lo[3];
      a[f][4] = hi[0]; a[f][5] = hi[1]; a[f][6] = hi[2]; a[f][7] = hi[3];
      v4i lo2 = *(const v4i*)(Bsm + boff[f][0]);
      v4i hi2 = *(const v4i*)(Bsm + boff[f][1]);
      b[f][0] = lo2[0]; b[f][1] = lo2[1]; b[f][2] = lo2[2]; b[f][3] = lo2[3];
      b[f][4] = hi2[0]; b[f][5] = hi2[1]; b[f][6] = hi2[2]; b[f][7] = hi2[3];
    }
    v4f sx[4];
#pragma unroll
    for (int f = 0; f < 4; ++f) sx[f] = *(const v4f*)(Ssm + kb * 128 + soff[f]);

#pragma unroll
    for (int f = 0; f < 4; ++f) {
#pragma unroll
      for (int g = 0; g < 4; ++g) {
        const v4f z = (v4f){0.f, 0.f, 0.f, 0.f};
        // unit e8m0 scales (0x7F = 2^0): plain fp8 K=128 dot at MX rate
        v4f p = __builtin_amdgcn_mfma_scale_f32_16x16x128_f8f6f4(
            a[f], b[g], z, 0, 0, 0, 0x7f7f7f7f, 0, 0x7f7f7f7f);
        acc[f][g] += sx[f] * p;  // exact f32 combined scale, per K=128 block
      }
    }
    __syncthreads();  // protect LDS before next stage
  }

  // ---- epilogue: C/D layout col = lane&15, row = quad*4 + reg ----
#pragma unroll
  for (int f = 0; f < 4; ++f) {
#pragma unroll
    for (int r = 0; r < 4; ++r) {
      const long long row = mtile * 128 + wm * 64 + f * 16 + quad * 4 + r;
      float* po = out + row * N + ntile * 128 + wn * 64 + l15;
#pragma unroll
      for (int g = 0; g < 4; ++g) po[g * 16] = acc[f][g][r];
    }
  }
}

extern "C" void kernel_launch(void* const* d_in, const int* in_sizes, int n_in,
                              void* d_out, int out_size, void* d_ws, size_t ws_size,
                              hipStream_t stream) {
  const float* x   = (const float*)d_in[0];  // [M,K]
  const float* w   = (const float*)d_in[1];  // [N,K]
  const float* wsc = (const float*)d_in[2];  // [NB,KB]
  float* out = (float*)d_out;                // [M,N] f32

  unsigned char* ws = (unsigned char*)d_ws;
  unsigned char* xq = ws;                                  // 32 MB
  unsigned char* wq = ws + (size_t)M * K;                  // 16 MB
  float* xs_t = (float*)(ws + (size_t)M * K + (size_t)N * K);  // 1 MB [KB][M]

  quant_x_kernel<<<M * KB / 8, 256, 0, stream>>>(x, xq, xs_t);
  quant_w_kernel<<<(N * (long long)K) / 1024, 256, 0, stream>>>(w, wq);
  gemm_fp8_kernel<<<dim3(N / 128, M / 128), 256, 0, stream>>>(xq, wq, xs_t, wsc, out);
}